// Round 12
// baseline (1736.831 us; speedup 1.0000x reference)
//
#include <hip/hip_runtime.h>
#include <math.h>

#define B_   64
#define MD   1024
#define H_   16
#define D_   64
#define LNEPS 1e-5f

// ---------------------------------------------------------------------------
// ws layout (floats):
//   q      [64][1024]
//   wtilT  [64][1024][16]     w̃T[b,m,h] = sum_d Wk[m, h*64+d] * q[b,h,d]
//   scores [64][16][sfull]
//   concat [64][1024]
//   integ  [64][1024]
//   fcwt   [1024][1024]       fc_weight transposed
// LESSON (R9): LDS row pad must be a multiple of 4 floats (16 B) or float4
// LDS ops lose b128 alignment and get split -> ~4x LDS instructions.
// LESSON (R10): depth-2 reg prefetch regressed; latency depth not the binder.
// LESSON (R11): per-epoch model showed LDS pipe (2.6us) ~ HBM (3.0us) per
// epoch, partially overlapped -> ~1.5x HBM floor. Fix: remove LDS entirely.
// ---------------------------------------------------------------------------

__device__ __forceinline__ float waveMax(float v) {
    #pragma unroll
    for (int off = 32; off > 0; off >>= 1) v = fmaxf(v, __shfl_xor(v, off, 64));
    return v;
}
__device__ __forceinline__ float waveSum(float v) {
    #pragma unroll
    for (int off = 32; off > 0; off >>= 1) v += __shfl_xor(v, off, 64);
    return v;
}

// ---- Kernel A: q[b, col] = sum_m x[b, idx, m] * Wq[m, col] -----------------
// grid (4 col-chunks, 64 b), block 256
__global__ void k_q(const float* __restrict__ x, const float* __restrict__ wq,
                    const int* __restrict__ idxp, float* __restrict__ qout, int sfull) {
    const int tid = threadIdx.x;
    const int col = blockIdx.x * 256 + tid;
    const int b   = blockIdx.y;
    const int idx = *idxp;
    const float* xr = x + ((size_t)b * sfull + idx) * MD;   // uniform -> scalar loads
    float a0 = 0.f, a1 = 0.f, a2 = 0.f, a3 = 0.f;
    for (int m = 0; m < MD; m += 4) {
        a0 += xr[m]     * wq[(size_t)m * MD + col];
        a1 += xr[m + 1] * wq[(size_t)(m + 1) * MD + col];
        a2 += xr[m + 2] * wq[(size_t)(m + 2) * MD + col];
        a3 += xr[m + 3] * wq[(size_t)(m + 3) * MD + col];
    }
    qout[(size_t)b * MD + col] = (a0 + a1) + (a2 + a3);
}

// ---- Kernel B: wtilT[b,m,h] = sum_d Wk[m, h*64+d] * q[b, h*64+d] -----------
// grid (16 h, 32 b-groups of 2), block 256. Writes TRANSPOSED layout so
// k_scores can read 16 h for one m as one contiguous 64-B uniform load.
__global__ void k_wtil(const float* __restrict__ wk, const float* __restrict__ q,
                       float* __restrict__ wtilT) {
    const int tid = threadIdx.x;
    const int h  = blockIdx.x;
    const int b0 = blockIdx.y * 2;
    for (int mi = 0; mi < 4; ++mi) {
        const int m = mi * 256 + tid;
        const float4* wrow = (const float4*)(wk + (size_t)m * MD + h * D_);
        float4 wv[16];
        #pragma unroll
        for (int j = 0; j < 16; ++j) wv[j] = wrow[j];
        #pragma unroll
        for (int bb = 0; bb < 2; ++bb) {
            const float* qh = q + (size_t)(b0 + bb) * MD + h * D_;  // uniform -> s_load
            float acc = 0.f;
            #pragma unroll
            for (int j = 0; j < 16; ++j)
                acc += wv[j].x * qh[4*j] + wv[j].y * qh[4*j+1]
                     + wv[j].z * qh[4*j+2] + wv[j].w * qh[4*j+3];
            wtilT[((size_t)(b0 + bb) * MD + m) * H_ + h] = acc;
        }
    }
}

// ---- Kernel P1: scores[b,h,s] = (x[b,s,:] . wtil[b,h,:]) / 8 ---------------
// grid (64 b, 16 s-tiles), block 256 (4 waves).  v11: ZERO LDS.
// Lane <-> s-row. Per 32-col chunk: 8 strided global_load_dwordx4 (lane reads
// its own row's full 128-B line once -> exact 1x fetch) + 512 FMA where the
// W operand comes from wave-uniform loads of wtilT (16 h contiguous per m ->
// scalar s_load, SGPR operand in v_fmac). LDS ops/chunk: 57 -> 0; the LDS
// pipe term that bound R4..R11 is gone. 16 waves/CU for HBM overlap.
// Reg double-buffer (named A/B, static idx), phase-ring channel stagger.
__global__ __launch_bounds__(256) void k_scores(
        const float* __restrict__ x, const float* __restrict__ wtilT,
        const int* __restrict__ idxp, float* __restrict__ scores, int sfull) {
    const int tid  = threadIdx.x;
    const int w    = tid >> 6;
    const int lane = tid & 63;
    const int b    = blockIdx.x;
    const int sblk = blockIdx.y * 256;
    const int S    = *idxp + 1;
    if (sblk >= S) return;

    const int srow = sblk + w * 64 + lane;
    const int lrow = srow < S ? srow : S - 1;        // clamp: no OOB, store guarded
    const float*  xrow = x + ((size_t)b * sfull + lrow) * MD;
    const float4* wt   = (const float4*)(wtilT + (size_t)b * MD * H_);

    // per-wave chunk-ring phase: decorrelate HBM channel usage (R11: real, small)
    const int phase = (b + blockIdx.y * 8 + w) & 31;
#define MCOF(T) ((((T) + phase) & 31) * 32)

    float acc[16] = {};
    float4 xA[8], xB[8];

#define ISSUE(BUF, MC) do {                                                    \
        _Pragma("unroll")                                                      \
        for (int j = 0; j < 8; ++j)                                            \
            BUF[j] = *(const float4*)(xrow + (MC) + j * 4);                    \
    } while (0)

    // 512 FMA vs wave-uniform W: w from SGPR (1 sgpr operand per VALU ok)
#define COMPUTE(BUF, MC) do {                                                  \
        _Pragma("unroll")                                                      \
        for (int mm = 0; mm < 8; ++mm) {                                       \
            const float4 xv = BUF[mm];                                         \
            _Pragma("unroll")                                                  \
            for (int qq = 0; qq < 4; ++qq) {                                   \
                const float xm = (qq == 0) ? xv.x : (qq == 1) ? xv.y           \
                               : (qq == 2) ? xv.z : xv.w;                      \
                const float4* wr = wt + (size_t)((MC) + mm * 4 + qq) * 4;      \
                const float4 w0 = wr[0], w1 = wr[1], w2 = wr[2], w3 = wr[3];   \
                acc[0]  += xm * w0.x; acc[1]  += xm * w0.y;                    \
                acc[2]  += xm * w0.z; acc[3]  += xm * w0.w;                    \
                acc[4]  += xm * w1.x; acc[5]  += xm * w1.y;                    \
                acc[6]  += xm * w1.z; acc[7]  += xm * w1.w;                    \
                acc[8]  += xm * w2.x; acc[9]  += xm * w2.y;                    \
                acc[10] += xm * w2.z; acc[11] += xm * w2.w;                    \
                acc[12] += xm * w3.x; acc[13] += xm * w3.y;                    \
                acc[14] += xm * w3.z; acc[15] += xm * w3.w;                    \
            }                                                                  \
        }                                                                      \
    } while (0)

    ISSUE(xA, MCOF(0));
    for (int t = 0; t < 32; t += 2) {
        if (t + 1 < 32) ISSUE(xB, MCOF(t + 1));
        COMPUTE(xA, MCOF(t));
        if (t + 2 < 32) ISSUE(xA, MCOF(t + 2));
        COMPUTE(xB, MCOF(t + 1));
    }
#undef ISSUE
#undef COMPUTE
#undef MCOF

    if (srow < S) {
        #pragma unroll
        for (int h = 0; h < 16; ++h)
            scores[((size_t)b * H_ + h) * sfull + srow] = acc[h] * 0.125f;
    }
}

// ---- Kernel C: softmax over s + sparse gather y = attn^T x + Wv projection -
// grid (16 h, 64 b), block 256
__global__ void k_attn(const float* __restrict__ x, const float* __restrict__ scores,
                       const float* __restrict__ wv, const int* __restrict__ idxp,
                       float* __restrict__ concat, int sfull) {
    __shared__ float red[8];
    __shared__ int   scanw[4];
    __shared__ int   lidx[4096];
    __shared__ float lw[4096];
    __shared__ float ylds[1024];
    __shared__ float pred[256];

    const int tid = threadIdx.x;
    const int h = blockIdx.x, b = blockIdx.y;
    const int S = *idxp + 1;
    const float* sc = scores + ((size_t)b * H_ + h) * sfull;

    float ls[16];
    float mx = -INFINITY;
    #pragma unroll
    for (int k = 0; k < 16; ++k) {
        int s = tid + 256 * k;
        if (s < S) { ls[k] = sc[s]; mx = fmaxf(mx, ls[k]); }
        else ls[k] = -INFINITY;
    }
    // block max
    mx = waveMax(mx);
    const int wid = tid >> 6, lane = tid & 63;
    if (lane == 0) red[wid] = mx;
    __syncthreads();
    mx = fmaxf(fmaxf(red[0], red[1]), fmaxf(red[2], red[3]));

    // denom + significant count (exp(s-max) <= 1.7e-15 contributes nothing)
    float sum = 0.f; int cnt = 0;
    #pragma unroll
    for (int k = 0; k < 16; ++k) {
        if (ls[k] > -INFINITY) {
            float e = ls[k] - mx;
            sum += expf(e);
            if (e > -34.f) ++cnt;
        }
    }
    sum = waveSum(sum);
    __syncthreads();
    if (lane == 0) red[4 + wid] = sum;
    __syncthreads();
    const float inv = 1.f / (red[4] + red[5] + red[6] + red[7]);

    // deterministic compaction: wave-level shfl scan + cross-wave LDS (1 barrier)
    int inc = cnt;
    #pragma unroll
    for (int off = 1; off < 64; off <<= 1) {
        int t = __shfl_up(inc, off, 64);
        if (lane >= off) inc += t;
    }
    if (lane == 63) scanw[wid] = inc;
    __syncthreads();
    int wbase = 0, total = 0;
    #pragma unroll
    for (int ww = 0; ww < 4; ++ww) {
        int t = scanw[ww];
        if (ww < wid) wbase += t;
        total += t;
    }
    int pos = wbase + inc - cnt;
    #pragma unroll
    for (int k = 0; k < 16; ++k) {
        if (ls[k] > -INFINITY) {
            float e = ls[k] - mx;
            if (e > -34.f) { lidx[pos] = tid + 256 * k; lw[pos] = expf(e) * inv; ++pos; }
        }
    }
    __syncthreads();

    // y[m] = sum_{significant s} attn * x[b,s,m]  (typically 1-3 rows)
    float4 acc = make_float4(0.f, 0.f, 0.f, 0.f);
    const float* xb = x + (size_t)b * sfull * MD;
    for (int e = 0; e < total; ++e) {
        int s = lidx[e]; float w = lw[e];
        float4 xv = *(const float4*)(xb + (size_t)s * MD + tid * 4);
        acc.x += w * xv.x; acc.y += w * xv.y; acc.z += w * xv.z; acc.w += w * xv.w;
    }
    *(float4*)(&ylds[tid * 4]) = acc;
    __syncthreads();

    // head_out[d] = sum_m y[m] * Wv[m, h*64+d]
    const int d = tid & 63, g = tid >> 6;
    const float* wcol = wv + (size_t)h * D_ + d;
    float part = 0.f;
    for (int m = g * 256; m < g * 256 + 256; ++m)
        part += ylds[m] * wcol[(size_t)m * MD];
    pred[tid] = part;
    __syncthreads();
    if (tid < 64) {
        float v = pred[tid] + pred[tid + 64] + pred[tid + 128] + pred[tid + 192];
        concat[(size_t)b * MD + h * D_ + tid] = v;
    }
}

// ---- Kernel T: fcwt[m][n] = fcW[n][m] --------------------------------------
__global__ void k_transpose(const float* __restrict__ a, float* __restrict__ at) {
    __shared__ float t[32][33];
    const int bx = blockIdx.x * 32, by = blockIdx.y * 32;
    const int tx = threadIdx.x & 31, ty = threadIdx.x >> 5;  // 32x8
    for (int r = ty; r < 32; r += 8)
        t[r][tx] = a[(size_t)(by + r) * MD + bx + tx];
    __syncthreads();
    for (int r = ty; r < 32; r += 8)
        at[(size_t)(bx + r) * MD + by + tx] = t[tx][r];
}

// ---- Kernel D: integ[b,n] = sum_m concat[b,m] * fcW[n,m] + bias[n] ---------
// grid (64 b, 16 n-chunks of 64), block 256: 4-way m-split + LDS reduce.
__global__ void k_fc(const float* __restrict__ concat, const float* __restrict__ fcwt,
                     const float* __restrict__ bias, float* __restrict__ integ) {
    __shared__ float c[1024];
    __shared__ float pred[256];
    const int tid = threadIdx.x, b = blockIdx.x;
    const int n0 = blockIdx.y * 64;
    const int nl = tid & 63, mg = tid >> 6;
    #pragma unroll
    for (int k = 0; k < 4; ++k) c[tid + 256 * k] = concat[(size_t)b * MD + tid + 256 * k];
    __syncthreads();
    const int mbase = mg * 256;
    float a0 = 0.f, a1 = 0.f, a2 = 0.f, a3 = 0.f;
    for (int m = 0; m < 256; m += 4) {
        a0 += c[mbase + m]     * fcwt[(size_t)(mbase + m) * MD + n0 + nl];
        a1 += c[mbase + m + 1] * fcwt[(size_t)(mbase + m + 1) * MD + n0 + nl];
        a2 += c[mbase + m + 2] * fcwt[(size_t)(mbase + m + 2) * MD + n0 + nl];
        a3 += c[mbase + m + 3] * fcwt[(size_t)(mbase + m + 3) * MD + n0 + nl];
    }
    pred[tid] = (a0 + a1) + (a2 + a3);
    __syncthreads();
    if (tid < 64)
        integ[(size_t)b * MD + n0 + tid] =
            pred[tid] + pred[tid + 64] + pred[tid + 128] + pred[tid + 192] + bias[n0 + tid];
}

// ---- Kernel E: LayerNorm ---------------------------------------------------
__global__ void k_ln(const float* __restrict__ integ, const float* __restrict__ gamma,
                     const float* __restrict__ beta, float* __restrict__ out) {
    __shared__ float red[8];
    const int tid = threadIdx.x, b = blockIdx.x;
    float v[4];
    #pragma unroll
    for (int k = 0; k < 4; ++k) v[k] = integ[(size_t)b * MD + tid + 256 * k];
    float s = v[0] + v[1] + v[2] + v[3];
    s = waveSum(s);
    const int wid = tid >> 6, lane = tid & 63;
    if (lane == 0) red[wid] = s;
    __syncthreads();
    const float mean = (red[0] + red[1] + red[2] + red[3]) * (1.f / MD);
    float q = 0.f;
    #pragma unroll
    for (int k = 0; k < 4; ++k) { float d = v[k] - mean; q += d * d; }
    q = waveSum(q);
    __syncthreads();
    if (lane == 0) red[4 + wid] = q;
    __syncthreads();
    const float var = (red[4] + red[5] + red[6] + red[7]) * (1.f / MD);
    const float rs = rsqrtf(var + LNEPS);
    #pragma unroll
    for (int k = 0; k < 4; ++k) {
        int i = tid + 256 * k;
        out[(size_t)b * MD + i] = (v[k] - mean) * rs * gamma[i] + beta[i];
    }
}

extern "C" void kernel_launch(void* const* d_in, const int* in_sizes, int n_in,
                              void* d_out, int out_size, void* d_ws, size_t ws_size,
                              hipStream_t stream) {
    const float* x     = (const float*)d_in[0];
    const float* wq    = (const float*)d_in[1];
    const float* wk    = (const float*)d_in[2];
    const float* wvp   = (const float*)d_in[3];
    const float* fcw   = (const float*)d_in[4];
    const float* fcb   = (const float*)d_in[5];
    const float* gamma = (const float*)d_in[6];
    const float* beta  = (const float*)d_in[7];
    const int*   idxp  = (const int*)d_in[8];
    float* out = (float*)d_out;

    const int sfull = in_sizes[0] / (B_ * MD);   // 4096

    float* q      = (float*)d_ws;
    float* wtilT  = q      + (size_t)B_ * MD;
    float* scores = wtilT  + (size_t)B_ * H_ * MD;
    float* concat = scores + (size_t)B_ * H_ * sfull;
    float* integ  = concat + (size_t)B_ * MD;
    float* fcwt   = integ  + (size_t)B_ * MD;

    hipLaunchKernelGGL(k_q,         dim3(4, 64),           dim3(256), 0, stream, x, wq, idxp, q, sfull);
    hipLaunchKernelGGL(k_wtil,      dim3(16, 32),          dim3(256), 0, stream, wk, q, wtilT);
    hipLaunchKernelGGL(k_scores,    dim3(B_, (sfull + 255) / 256), dim3(256), 0, stream, x, wtilT, idxp, scores, sfull);
    hipLaunchKernelGGL(k_transpose, dim3(32, 32),          dim3(256), 0, stream, fcw, fcwt);
    hipLaunchKernelGGL(k_attn,      dim3(H_, B_),          dim3(256), 0, stream, x, scores, wvp, idxp, concat, sfull);
    hipLaunchKernelGGL(k_fc,        dim3(64, 16),          dim3(256), 0, stream, concat, fcwt, fcb, integ);
    hipLaunchKernelGGL(k_ln,        dim3(B_),              dim3(256), 0, stream, integ, gamma, beta, out);
}

// Round 13
// 369.125 us; speedup vs baseline: 4.7053x; 4.7053x over previous
//
#include <hip/hip_runtime.h>
#include <math.h>

#define B_   64
#define MD   1024
#define H_   16
#define D_   64
#define LNEPS 1e-5f

// ---------------------------------------------------------------------------
// ws layout (floats):
//   q      [64][1024]
//   wtil   [64][16][1024]     w̃[b,h,m] = sum_d Wk[m, h*64+d] * q[b,h,d]
//   scores [64][16][sfull]
//   concat [64][1024]
//   integ  [64][1024]
//   fcwt   [1024][1024]       fc_weight transposed
// LESSON (R9):  LDS row pad must be a multiple of 4 floats (16 B) or b128
//               LDS ops get split -> ~4x LDS instructions.
// LESSON (R10): depth-2 reg prefetch regressed; latency depth not the binder.
// LESSON (R12): zero-LDS failed -- compiler treats tid-derived addrs as
//               divergent (no s_load), VGPR 256 -> 2.3 GB scratch spill.
// LESSON (R9 counter): grid size capped occupancy at 8 waves/CU for all
//               k=8 variants; this round tests 16 waves/CU via k=4.
// ---------------------------------------------------------------------------

__device__ __forceinline__ float waveMax(float v) {
    #pragma unroll
    for (int off = 32; off > 0; off >>= 1) v = fmaxf(v, __shfl_xor(v, off, 64));
    return v;
}
__device__ __forceinline__ float waveSum(float v) {
    #pragma unroll
    for (int off = 32; off > 0; off >>= 1) v += __shfl_xor(v, off, 64);
    return v;
}

// ---- Kernel A: q[b, col] = sum_m x[b, idx, m] * Wq[m, col] -----------------
// grid (4 col-chunks, 64 b), block 256
__global__ void k_q(const float* __restrict__ x, const float* __restrict__ wq,
                    const int* __restrict__ idxp, float* __restrict__ qout, int sfull) {
    const int tid = threadIdx.x;
    const int col = blockIdx.x * 256 + tid;
    const int b   = blockIdx.y;
    const int idx = *idxp;
    const float* xr = x + ((size_t)b * sfull + idx) * MD;   // uniform -> scalar loads
    float a0 = 0.f, a1 = 0.f, a2 = 0.f, a3 = 0.f;
    for (int m = 0; m < MD; m += 4) {
        a0 += xr[m]     * wq[(size_t)m * MD + col];
        a1 += xr[m + 1] * wq[(size_t)(m + 1) * MD + col];
        a2 += xr[m + 2] * wq[(size_t)(m + 2) * MD + col];
        a3 += xr[m + 3] * wq[(size_t)(m + 3) * MD + col];
    }
    qout[(size_t)b * MD + col] = (a0 + a1) + (a2 + a3);
}

// ---- Kernel B: wtil[b,h,m] = sum_d Wk[m, h*64+d] * q[b, h*64+d] ------------
// grid (16 h, 32 b-groups of 2), block 256
__global__ void k_wtil(const float* __restrict__ wk, const float* __restrict__ q,
                       float* __restrict__ wtil) {
    const int tid = threadIdx.x;
    const int h  = blockIdx.x;
    const int b0 = blockIdx.y * 2;
    for (int mi = 0; mi < 4; ++mi) {
        const int m = mi * 256 + tid;
        const float4* wrow = (const float4*)(wk + (size_t)m * MD + h * D_);
        float4 wv[16];
        #pragma unroll
        for (int j = 0; j < 16; ++j) wv[j] = wrow[j];
        #pragma unroll
        for (int bb = 0; bb < 2; ++bb) {
            const float* qh = q + (size_t)(b0 + bb) * MD + h * D_;  // uniform -> s_load
            float acc = 0.f;
            #pragma unroll
            for (int j = 0; j < 16; ++j)
                acc += wv[j].x * qh[4*j] + wv[j].y * qh[4*j+1]
                     + wv[j].z * qh[4*j+2] + wv[j].w * qh[4*j+3];
            wtil[((size_t)(b0 + bb) * H_ + h) * MD + m] = acc;
        }
    }
}

// ---- Kernel P1: scores[b,h,s] = (x[b,s,:] . wtil[b,h,:]) / 8 ---------------
// grid (64 b, 16 s-tiles), block 256 (4 waves).
// v13 = v5 body with k=4 rows/thread: wave owns 64 rows -> 4096 waves total
// -> 16 waves/CU (4/SIMD), double every earlier k=8 variant (grid-capped at
// 8/CU per R9's occupancy counter). More co-resident waves let one wave's
// ds-phase hide another's vmcnt wait. Pad 20 floats (b128-aligned, write
// banks at the b128 throughput floor). Zero barriers, depth-1 prefetch,
// phase-ring stagger (R11: -8us), XCD-b grid placement.
__global__ __launch_bounds__(256) void k_scores(
        const float* __restrict__ x, const float* __restrict__ wtil,
        const int* __restrict__ idxp, float* __restrict__ scores, int sfull) {
    __shared__ float Xw[4][64 * 20];   // per-wave: 64 rows x 16 m (+4 pad) = 5 KB
    __shared__ float Ww[4][16 * 20];   // per-wave: 16 h x 16 m (+4 pad) = 1.25 KB
    const int tid  = threadIdx.x;
    const int w    = tid >> 6;
    const int lane = tid & 63;
    const int sg   = lane & 15;      // s sub-index
    const int hg   = lane >> 4;      // h group
    const int b    = blockIdx.x;
    const int sblk = blockIdx.y * 256;
    const int s0   = sblk + w * 64;  // this wave's first row
    const int S    = *idxp + 1;
    if (sblk >= S) return;

    const float* xb = x    + (size_t)b * sfull * MD;
    const float* wb = wtil + (size_t)b * H_ * MD;

    float* Xs = Xw[w];
    float* Ws = Ww[w];

    const int csl = lane >> 2;       // 0..15 staging row within group
    const int cf4 = lane & 3;        // 0..3 float4 slot

    // per-wave chunk-ring phase: decorrelate HBM channel usage
    const int phase = (b + blockIdx.y * 4 + w) & 63;
#define MCOF(T) ((((T) + phase) & 63) * 16)

    float acc[4][4] = {};
    float4 nx[4];
    float4 nw;

#define ISSUE(MC) do {                                                         \
        _Pragma("unroll")                                                      \
        for (int i = 0; i < 4; ++i) {                                          \
            int sl = i * 16 + csl;                                             \
            int srow = s0 + sl;                                                \
            nx[i] = (srow < S)                                                 \
                ? *(const float4*)(xb + (size_t)srow * MD + (MC) + cf4 * 4)    \
                : make_float4(0.f, 0.f, 0.f, 0.f);                             \
        }                                                                      \
        nw = *(const float4*)(wb + (size_t)csl * MD + (MC) + cf4 * 4);         \
    } while (0)

    ISSUE(MCOF(0));

    for (int t = 0; t < 64; ++t) {
        // commit staged regs to this wave's LDS slice (in-order after last
        // chunk's ds_reads; wave-private so no cross-wave hazard)
        // NOTE i*16+csl covers rows 0..63 for i=0..3 with csl=lane>>2? csl is
        // 0..15 so rows i*16+csl cover 0..63 exactly once per lane-quad.
        #pragma unroll
        for (int i = 0; i < 4; ++i)
            *(float4*)(&Xs[(i * 16 + csl) * 20 + cf4 * 4]) = nx[i];
        *(float4*)(&Ws[csl * 20 + cf4 * 4]) = nw;

        if (t + 1 < 64) ISSUE(MCOF(t + 1));   // prefetch next ring chunk

        // compute 4s x 4h x 16m, in two 8-m halves to cap register pressure
        #pragma unroll
        for (int half = 0; half < 2; ++half) {
            float4 wrh[4][2];
            #pragma unroll
            for (int j = 0; j < 4; ++j) {
                #pragma unroll
                for (int mm = 0; mm < 2; ++mm)
                    wrh[j][mm] = *(const float4*)(&Ws[(hg + 4 * j) * 20 + (half * 2 + mm) * 4]);
            }
            #pragma unroll
            for (int k = 0; k < 4; ++k) {
                const float4 xr0 = *(const float4*)(&Xs[(sg + 16 * k) * 20 + (half * 2) * 4]);
                const float4 xr1 = *(const float4*)(&Xs[(sg + 16 * k) * 20 + (half * 2 + 1) * 4]);
                #pragma unroll
                for (int j = 0; j < 4; ++j) {
                    acc[k][j] += xr0.x * wrh[j][0].x + xr0.y * wrh[j][0].y
                               + xr0.z * wrh[j][0].z + xr0.w * wrh[j][0].w
                               + xr1.x * wrh[j][1].x + xr1.y * wrh[j][1].y
                               + xr1.z * wrh[j][1].z + xr1.w * wrh[j][1].w;
                }
            }
        }
    }
#undef ISSUE
#undef MCOF

    #pragma unroll
    for (int k = 0; k < 4; ++k) {
        const int s = s0 + sg + 16 * k;
        if (s < S) {
            #pragma unroll
            for (int j = 0; j < 4; ++j)
                scores[((size_t)b * H_ + (hg + 4 * j)) * sfull + s] = acc[k][j] * 0.125f;
        }
    }
}

// ---- Kernel C: softmax over s + sparse gather y = attn^T x + Wv projection -
// grid (16 h, 64 b), block 256
__global__ void k_attn(const float* __restrict__ x, const float* __restrict__ scores,
                       const float* __restrict__ wv, const int* __restrict__ idxp,
                       float* __restrict__ concat, int sfull) {
    __shared__ float red[8];
    __shared__ int   scanw[4];
    __shared__ int   lidx[4096];
    __shared__ float lw[4096];
    __shared__ float ylds[1024];
    __shared__ float pred[256];

    const int tid = threadIdx.x;
    const int h = blockIdx.x, b = blockIdx.y;
    const int S = *idxp + 1;
    const float* sc = scores + ((size_t)b * H_ + h) * sfull;

    float ls[16];
    float mx = -INFINITY;
    #pragma unroll
    for (int k = 0; k < 16; ++k) {
        int s = tid + 256 * k;
        if (s < S) { ls[k] = sc[s]; mx = fmaxf(mx, ls[k]); }
        else ls[k] = -INFINITY;
    }
    // block max
    mx = waveMax(mx);
    const int wid = tid >> 6, lane = tid & 63;
    if (lane == 0) red[wid] = mx;
    __syncthreads();
    mx = fmaxf(fmaxf(red[0], red[1]), fmaxf(red[2], red[3]));

    // denom + significant count (exp(s-max) <= 1.7e-15 contributes nothing)
    float sum = 0.f; int cnt = 0;
    #pragma unroll
    for (int k = 0; k < 16; ++k) {
        if (ls[k] > -INFINITY) {
            float e = ls[k] - mx;
            sum += expf(e);
            if (e > -34.f) ++cnt;
        }
    }
    sum = waveSum(sum);
    __syncthreads();
    if (lane == 0) red[4 + wid] = sum;
    __syncthreads();
    const float inv = 1.f / (red[4] + red[5] + red[6] + red[7]);

    // deterministic compaction: wave-level shfl scan + cross-wave LDS (1 barrier)
    int inc = cnt;
    #pragma unroll
    for (int off = 1; off < 64; off <<= 1) {
        int t = __shfl_up(inc, off, 64);
        if (lane >= off) inc += t;
    }
    if (lane == 63) scanw[wid] = inc;
    __syncthreads();
    int wbase = 0, total = 0;
    #pragma unroll
    for (int ww = 0; ww < 4; ++ww) {
        int t = scanw[ww];
        if (ww < wid) wbase += t;
        total += t;
    }
    int pos = wbase + inc - cnt;
    #pragma unroll
    for (int k = 0; k < 16; ++k) {
        if (ls[k] > -INFINITY) {
            float e = ls[k] - mx;
            if (e > -34.f) { lidx[pos] = tid + 256 * k; lw[pos] = expf(e) * inv; ++pos; }
        }
    }
    __syncthreads();

    // y[m] = sum_{significant s} attn * x[b,s,m]  (typically 1-3 rows)
    float4 acc = make_float4(0.f, 0.f, 0.f, 0.f);
    const float* xb = x + (size_t)b * sfull * MD;
    for (int e = 0; e < total; ++e) {
        int s = lidx[e]; float w = lw[e];
        float4 xv = *(const float4*)(xb + (size_t)s * MD + tid * 4);
        acc.x += w * xv.x; acc.y += w * xv.y; acc.z += w * xv.z; acc.w += w * xv.w;
    }
    *(float4*)(&ylds[tid * 4]) = acc;
    __syncthreads();

    // head_out[d] = sum_m y[m] * Wv[m, h*64+d]
    const int d = tid & 63, g = tid >> 6;
    const float* wcol = wv + (size_t)h * D_ + d;
    float part = 0.f;
    for (int m = g * 256; m < g * 256 + 256; ++m)
        part += ylds[m] * wcol[(size_t)m * MD];
    pred[tid] = part;
    __syncthreads();
    if (tid < 64) {
        float v = pred[tid] + pred[tid + 64] + pred[tid + 128] + pred[tid + 192];
        concat[(size_t)b * MD + h * D_ + tid] = v;
    }
}

// ---- Kernel T: fcwt[m][n] = fcW[n][m] --------------------------------------
__global__ void k_transpose(const float* __restrict__ a, float* __restrict__ at) {
    __shared__ float t[32][33];
    const int bx = blockIdx.x * 32, by = blockIdx.y * 32;
    const int tx = threadIdx.x & 31, ty = threadIdx.x >> 5;  // 32x8
    for (int r = ty; r < 32; r += 8)
        t[r][tx] = a[(size_t)(by + r) * MD + bx + tx];
    __syncthreads();
    for (int r = ty; r < 32; r += 8)
        at[(size_t)(bx + r) * MD + by + tx] = t[tx][r];
}

// ---- Kernel D: integ[b,n] = sum_m concat[b,m] * fcW[n,m] + bias[n] ---------
// grid (64 b, 16 n-chunks of 64), block 256: 4-way m-split + LDS reduce.
__global__ void k_fc(const float* __restrict__ concat, const float* __restrict__ fcwt,
                     const float* __restrict__ bias, float* __restrict__ integ) {
    __shared__ float c[1024];
    __shared__ float pred[256];
    const int tid = threadIdx.x, b = blockIdx.x;
    const int n0 = blockIdx.y * 64;
    const int nl = tid & 63, mg = tid >> 6;
    #pragma unroll
    for (int k = 0; k < 4; ++k) c[tid + 256 * k] = concat[(size_t)b * MD + tid + 256 * k];
    __syncthreads();
    const int mbase = mg * 256;
    float a0 = 0.f, a1 = 0.f, a2 = 0.f, a3 = 0.f;
    for (int m = 0; m < 256; m += 4) {
        a0 += c[mbase + m]     * fcwt[(size_t)(mbase + m) * MD + n0 + nl];
        a1 += c[mbase + m + 1] * fcwt[(size_t)(mbase + m + 1) * MD + n0 + nl];
        a2 += c[mbase + m + 2] * fcwt[(size_t)(mbase + m + 2) * MD + n0 + nl];
        a3 += c[mbase + m + 3] * fcwt[(size_t)(mbase + m + 3) * MD + n0 + nl];
    }
    pred[tid] = (a0 + a1) + (a2 + a3);
    __syncthreads();
    if (tid < 64)
        integ[(size_t)b * MD + n0 + tid] =
            pred[tid] + pred[tid + 64] + pred[tid + 128] + pred[tid + 192] + bias[n0 + tid];
}

// ---- Kernel E: LayerNorm ---------------------------------------------------
__global__ void k_ln(const float* __restrict__ integ, const float* __restrict__ gamma,
                     const float* __restrict__ beta, float* __restrict__ out) {
    __shared__ float red[8];
    const int tid = threadIdx.x, b = blockIdx.x;
    float v[4];
    #pragma unroll
    for (int k = 0; k < 4; ++k) v[k] = integ[(size_t)b * MD + tid + 256 * k];
    float s = v[0] + v[1] + v[2] + v[3];
    s = waveSum(s);
    const int wid = tid >> 6, lane = tid & 63;
    if (lane == 0) red[wid] = s;
    __syncthreads();
    const float mean = (red[0] + red[1] + red[2] + red[3]) * (1.f / MD);
    float q = 0.f;
    #pragma unroll
    for (int k = 0; k < 4; ++k) { float d = v[k] - mean; q += d * d; }
    q = waveSum(q);
    __syncthreads();
    if (lane == 0) red[4 + wid] = q;
    __syncthreads();
    const float var = (red[4] + red[5] + red[6] + red[7]) * (1.f / MD);
    const float rs = rsqrtf(var + LNEPS);
    #pragma unroll
    for (int k = 0; k < 4; ++k) {
        int i = tid + 256 * k;
        out[(size_t)b * MD + i] = (v[k] - mean) * rs * gamma[i] + beta[i];
    }
}

extern "C" void kernel_launch(void* const* d_in, const int* in_sizes, int n_in,
                              void* d_out, int out_size, void* d_ws, size_t ws_size,
                              hipStream_t stream) {
    const float* x     = (const float*)d_in[0];
    const float* wq    = (const float*)d_in[1];
    const float* wk    = (const float*)d_in[2];
    const float* wvp   = (const float*)d_in[3];
    const float* fcw   = (const float*)d_in[4];
    const float* fcb   = (const float*)d_in[5];
    const float* gamma = (const float*)d_in[6];
    const float* beta  = (const float*)d_in[7];
    const int*   idxp  = (const int*)d_in[8];
    float* out = (float*)d_out;

    const int sfull = in_sizes[0] / (B_ * MD);   // 4096

    float* q      = (float*)d_ws;
    float* wtil   = q      + (size_t)B_ * MD;
    float* scores = wtil   + (size_t)B_ * H_ * MD;
    float* concat = scores + (size_t)B_ * H_ * sfull;
    float* integ  = concat + (size_t)B_ * MD;
    float* fcwt   = integ  + (size_t)B_ * MD;

    hipLaunchKernelGGL(k_q,         dim3(4, 64),           dim3(256), 0, stream, x, wq, idxp, q, sfull);
    hipLaunchKernelGGL(k_wtil,      dim3(16, 32),          dim3(256), 0, stream, wk, q, wtil);
    hipLaunchKernelGGL(k_scores,    dim3(B_, (sfull + 255) / 256), dim3(256), 0, stream, x, wtil, idxp, scores, sfull);
    hipLaunchKernelGGL(k_transpose, dim3(32, 32),          dim3(256), 0, stream, fcw, fcwt);
    hipLaunchKernelGGL(k_attn,      dim3(H_, B_),          dim3(256), 0, stream, x, scores, wvp, idxp, concat, sfull);
    hipLaunchKernelGGL(k_fc,        dim3(64, 16),          dim3(256), 0, stream, concat, fcwt, fcb, integ);
    hipLaunchKernelGGL(k_ln,        dim3(B_),              dim3(256), 0, stream, integ, gamma, beta, out);
}

// Round 14
// 363.221 us; speedup vs baseline: 4.7818x; 1.0163x over previous
//
#include <hip/hip_runtime.h>
#include <math.h>

#define B_   64
#define MD   1024
#define H_   16
#define D_   64
#define LNEPS 1e-5f

// ---------------------------------------------------------------------------
// ws layout (floats):
//   q      [64][1024]
//   wtil   [64][16][1024]     w̃[b,h,m] = sum_d Wk[m, h*64+d] * q[b,h,d]
//   scores [64][16][sfull]
//   concat [64][1024]
//   integ  [64][1024]
//   fcwt   [1024][1024]       fc_weight transposed
// LESSON (R9):  LDS row pad must be a multiple of 4 floats (16 B).
// LESSON (R10): depth-2 reg prefetch regressed (+23 us).
// LESSON (R12): zero-LDS failed -- tid-derived addrs stay divergent, spill.
// LESSON (R13): occupancy (8 vs 16 waves/CU) is NOT the binder; observed ~=
//   HBM + 0.65 * (LDS_ops * 12cyc) across ALL variants. Only lever left:
//   fewer LDS ops per FMA -> k=16 (65 ops / 1024 FMA -> LDS term 83 us).
// ---------------------------------------------------------------------------

__device__ __forceinline__ float waveMax(float v) {
    #pragma unroll
    for (int off = 32; off > 0; off >>= 1) v = fmaxf(v, __shfl_xor(v, off, 64));
    return v;
}
__device__ __forceinline__ float waveSum(float v) {
    #pragma unroll
    for (int off = 32; off > 0; off >>= 1) v += __shfl_xor(v, off, 64);
    return v;
}

// ---- Kernel A: q[b, col] = sum_m x[b, idx, m] * Wq[m, col] -----------------
// grid (4 col-chunks, 64 b), block 256
__global__ void k_q(const float* __restrict__ x, const float* __restrict__ wq,
                    const int* __restrict__ idxp, float* __restrict__ qout, int sfull) {
    const int tid = threadIdx.x;
    const int col = blockIdx.x * 256 + tid;
    const int b   = blockIdx.y;
    const int idx = *idxp;
    const float* xr = x + ((size_t)b * sfull + idx) * MD;   // uniform -> scalar loads
    float a0 = 0.f, a1 = 0.f, a2 = 0.f, a3 = 0.f;
    for (int m = 0; m < MD; m += 4) {
        a0 += xr[m]     * wq[(size_t)m * MD + col];
        a1 += xr[m + 1] * wq[(size_t)(m + 1) * MD + col];
        a2 += xr[m + 2] * wq[(size_t)(m + 2) * MD + col];
        a3 += xr[m + 3] * wq[(size_t)(m + 3) * MD + col];
    }
    qout[(size_t)b * MD + col] = (a0 + a1) + (a2 + a3);
}

// ---- Kernel B: wtil[b,h,m] = sum_d Wk[m, h*64+d] * q[b, h*64+d] ------------
// grid (16 h, 32 b-groups of 2), block 256
__global__ void k_wtil(const float* __restrict__ wk, const float* __restrict__ q,
                       float* __restrict__ wtil) {
    const int tid = threadIdx.x;
    const int h  = blockIdx.x;
    const int b0 = blockIdx.y * 2;
    for (int mi = 0; mi < 4; ++mi) {
        const int m = mi * 256 + tid;
        const float4* wrow = (const float4*)(wk + (size_t)m * MD + h * D_);
        float4 wv[16];
        #pragma unroll
        for (int j = 0; j < 16; ++j) wv[j] = wrow[j];
        #pragma unroll
        for (int bb = 0; bb < 2; ++bb) {
            const float* qh = q + (size_t)(b0 + bb) * MD + h * D_;  // uniform -> s_load
            float acc = 0.f;
            #pragma unroll
            for (int j = 0; j < 16; ++j)
                acc += wv[j].x * qh[4*j] + wv[j].y * qh[4*j+1]
                     + wv[j].z * qh[4*j+2] + wv[j].w * qh[4*j+3];
            wtil[((size_t)(b0 + bb) * H_ + h) * MD + m] = acc;
        }
    }
}

// ---- Kernel P1: scores[b,h,s] = (x[b,s,:] . wtil[b,h,:]) / 8 ---------------
// grid (64 b, 4 s-tiles of 1024), block 256 (4 waves), 256 blocks = 1/CU.
// v14: k=16 rows/thread -- wave owns 256 rows. Per chunk/wave: 17 ds_writes
// + 48 ds_reads feed 1024 FMAs (65 LDS ops) -> LDS term ~83 us/CU, well
// below the ~195 us HBM term, so even with the measured partial overlap the
// kernel moves toward HBM-bound. 1 wave/SIMD; in-flight 70 KB/CU (>= ~55
// needed); loads for chunk t+1 issued a full chunk (~3 us) before their wait.
// VGPR ~190 (acc 64 + nx 64 + transients), static indexing throughout.
// Zero barriers, wave-private LDS (85 KB/block), phase-ring stagger, XCD-b.
__global__ __launch_bounds__(256, 1) void k_scores(
        const float* __restrict__ x, const float* __restrict__ wtil,
        const int* __restrict__ idxp, float* __restrict__ scores, int sfull) {
    __shared__ float Xw[4][256 * 20];  // per-wave: 256 rows x 16 m (+4 pad) = 20 KB
    __shared__ float Ww[4][16 * 20];   // per-wave: 16 h x 16 m (+4 pad) = 1.25 KB
    const int tid  = threadIdx.x;
    const int w    = tid >> 6;
    const int lane = tid & 63;
    const int sg   = lane & 15;      // s sub-index
    const int hg   = lane >> 4;      // h group
    const int b    = blockIdx.x;
    const int sblk = blockIdx.y * 1024;
    const int s0   = sblk + w * 256; // this wave's first row
    const int S    = *idxp + 1;
    if (sblk >= S) return;

    const float* xb = x    + (size_t)b * sfull * MD;
    const float* wb = wtil + (size_t)b * H_ * MD;

    float* Xs = Xw[w];
    float* Ws = Ww[w];

    const int csl = lane >> 2;       // 0..15 staging row within group
    const int cf4 = lane & 3;        // 0..3 float4 slot

    // per-wave chunk-ring phase: decorrelate HBM channel usage
    const int phase = (b + blockIdx.y * 16 + w * 4) & 63;
#define MCOF(T) ((((T) + phase) & 63) * 16)

    float acc[16][4] = {};
    float4 nx[16];
    float4 nw;

#define ISSUE(MC) do {                                                         \
        _Pragma("unroll")                                                      \
        for (int i = 0; i < 16; ++i) {                                         \
            int sl = i * 16 + csl;                                             \
            int srow = s0 + sl;                                                \
            nx[i] = (srow < S)                                                 \
                ? *(const float4*)(xb + (size_t)srow * MD + (MC) + cf4 * 4)    \
                : make_float4(0.f, 0.f, 0.f, 0.f);                             \
        }                                                                      \
        nw = *(const float4*)(wb + (size_t)csl * MD + (MC) + cf4 * 4);         \
    } while (0)

    ISSUE(MCOF(0));

    for (int t = 0; t < 64; ++t) {
        // commit staged regs to this wave's LDS slice (wave-private, in-order)
        #pragma unroll
        for (int i = 0; i < 16; ++i)
            *(float4*)(&Xs[(i * 16 + csl) * 20 + cf4 * 4]) = nx[i];
        *(float4*)(&Ws[csl * 20 + cf4 * 4]) = nw;

        if (t + 1 < 64) ISSUE(MCOF(t + 1));   // prefetch next ring chunk

        // compute 16s x 4h x 16m, in two 8-m halves to cap register pressure
        #pragma unroll
        for (int half = 0; half < 2; ++half) {
            float4 wrh[4][2];
            #pragma unroll
            for (int j = 0; j < 4; ++j) {
                #pragma unroll
                for (int mm = 0; mm < 2; ++mm)
                    wrh[j][mm] = *(const float4*)(&Ws[(hg + 4 * j) * 20 + (half * 2 + mm) * 4]);
            }
            #pragma unroll
            for (int k = 0; k < 16; ++k) {
                const float4 xr0 = *(const float4*)(&Xs[(sg + 16 * k) * 20 + (half * 2) * 4]);
                const float4 xr1 = *(const float4*)(&Xs[(sg + 16 * k) * 20 + (half * 2 + 1) * 4]);
                #pragma unroll
                for (int j = 0; j < 4; ++j) {
                    acc[k][j] += xr0.x * wrh[j][0].x + xr0.y * wrh[j][0].y
                               + xr0.z * wrh[j][0].z + xr0.w * wrh[j][0].w
                               + xr1.x * wrh[j][1].x + xr1.y * wrh[j][1].y
                               + xr1.z * wrh[j][1].z + xr1.w * wrh[j][1].w;
                }
            }
        }
    }
#undef ISSUE
#undef MCOF

    #pragma unroll
    for (int k = 0; k < 16; ++k) {
        const int s = s0 + sg + 16 * k;
        if (s < S) {
            #pragma unroll
            for (int j = 0; j < 4; ++j)
                scores[((size_t)b * H_ + (hg + 4 * j)) * sfull + s] = acc[k][j] * 0.125f;
        }
    }
}

// ---- Kernel C: softmax over s + sparse gather y = attn^T x + Wv projection -
// grid (16 h, 64 b), block 256
__global__ void k_attn(const float* __restrict__ x, const float* __restrict__ scores,
                       const float* __restrict__ wv, const int* __restrict__ idxp,
                       float* __restrict__ concat, int sfull) {
    __shared__ float red[8];
    __shared__ int   scanw[4];
    __shared__ int   lidx[4096];
    __shared__ float lw[4096];
    __shared__ float ylds[1024];
    __shared__ float pred[256];

    const int tid = threadIdx.x;
    const int h = blockIdx.x, b = blockIdx.y;
    const int S = *idxp + 1;
    const float* sc = scores + ((size_t)b * H_ + h) * sfull;

    float ls[16];
    float mx = -INFINITY;
    #pragma unroll
    for (int k = 0; k < 16; ++k) {
        int s = tid + 256 * k;
        if (s < S) { ls[k] = sc[s]; mx = fmaxf(mx, ls[k]); }
        else ls[k] = -INFINITY;
    }
    // block max
    mx = waveMax(mx);
    const int wid = tid >> 6, lane = tid & 63;
    if (lane == 0) red[wid] = mx;
    __syncthreads();
    mx = fmaxf(fmaxf(red[0], red[1]), fmaxf(red[2], red[3]));

    // denom + significant count (exp(s-max) <= 1.7e-15 contributes nothing)
    float sum = 0.f; int cnt = 0;
    #pragma unroll
    for (int k = 0; k < 16; ++k) {
        if (ls[k] > -INFINITY) {
            float e = ls[k] - mx;
            sum += expf(e);
            if (e > -34.f) ++cnt;
        }
    }
    sum = waveSum(sum);
    __syncthreads();
    if (lane == 0) red[4 + wid] = sum;
    __syncthreads();
    const float inv = 1.f / (red[4] + red[5] + red[6] + red[7]);

    // deterministic compaction: wave-level shfl scan + cross-wave LDS (1 barrier)
    int inc = cnt;
    #pragma unroll
    for (int off = 1; off < 64; off <<= 1) {
        int t = __shfl_up(inc, off, 64);
        if (lane >= off) inc += t;
    }
    if (lane == 63) scanw[wid] = inc;
    __syncthreads();
    int wbase = 0, total = 0;
    #pragma unroll
    for (int ww = 0; ww < 4; ++ww) {
        int t = scanw[ww];
        if (ww < wid) wbase += t;
        total += t;
    }
    int pos = wbase + inc - cnt;
    #pragma unroll
    for (int k = 0; k < 16; ++k) {
        if (ls[k] > -INFINITY) {
            float e = ls[k] - mx;
            if (e > -34.f) { lidx[pos] = tid + 256 * k; lw[pos] = expf(e) * inv; ++pos; }
        }
    }
    __syncthreads();

    // y[m] = sum_{significant s} attn * x[b,s,m]  (typically 1-3 rows)
    float4 acc = make_float4(0.f, 0.f, 0.f, 0.f);
    const float* xb = x + (size_t)b * sfull * MD;
    for (int e = 0; e < total; ++e) {
        int s = lidx[e]; float w = lw[e];
        float4 xv = *(const float4*)(xb + (size_t)s * MD + tid * 4);
        acc.x += w * xv.x; acc.y += w * xv.y; acc.z += w * xv.z; acc.w += w * xv.w;
    }
    *(float4*)(&ylds[tid * 4]) = acc;
    __syncthreads();

    // head_out[d] = sum_m y[m] * Wv[m, h*64+d]
    const int d = tid & 63, g = tid >> 6;
    const float* wcol = wv + (size_t)h * D_ + d;
    float part = 0.f;
    for (int m = g * 256; m < g * 256 + 256; ++m)
        part += ylds[m] * wcol[(size_t)m * MD];
    pred[tid] = part;
    __syncthreads();
    if (tid < 64) {
        float v = pred[tid] + pred[tid + 64] + pred[tid + 128] + pred[tid + 192];
        concat[(size_t)b * MD + h * D_ + tid] = v;
    }
}

// ---- Kernel T: fcwt[m][n] = fcW[n][m] --------------------------------------
__global__ void k_transpose(const float* __restrict__ a, float* __restrict__ at) {
    __shared__ float t[32][33];
    const int bx = blockIdx.x * 32, by = blockIdx.y * 32;
    const int tx = threadIdx.x & 31, ty = threadIdx.x >> 5;  // 32x8
    for (int r = ty; r < 32; r += 8)
        t[r][tx] = a[(size_t)(by + r) * MD + bx + tx];
    __syncthreads();
    for (int r = ty; r < 32; r += 8)
        at[(size_t)(bx + r) * MD + by + tx] = t[tx][r];
}

// ---- Kernel D: integ[b,n] = sum_m concat[b,m] * fcW[n,m] + bias[n] ---------
// grid (64 b, 16 n-chunks of 64), block 256: 4-way m-split + LDS reduce.
__global__ void k_fc(const float* __restrict__ concat, const float* __restrict__ fcwt,
                     const float* __restrict__ bias, float* __restrict__ integ) {
    __shared__ float c[1024];
    __shared__ float pred[256];
    const int tid = threadIdx.x, b = blockIdx.x;
    const int n0 = blockIdx.y * 64;
    const int nl = tid & 63, mg = tid >> 6;
    #pragma unroll
    for (int k = 0; k < 4; ++k) c[tid + 256 * k] = concat[(size_t)b * MD + tid + 256 * k];
    __syncthreads();
    const int mbase = mg * 256;
    float a0 = 0.f, a1 = 0.f, a2 = 0.f, a3 = 0.f;
    for (int m = 0; m < 256; m += 4) {
        a0 += c[mbase + m]     * fcwt[(size_t)(mbase + m) * MD + n0 + nl];
        a1 += c[mbase + m + 1] * fcwt[(size_t)(mbase + m + 1) * MD + n0 + nl];
        a2 += c[mbase + m + 2] * fcwt[(size_t)(mbase + m + 2) * MD + n0 + nl];
        a3 += c[mbase + m + 3] * fcwt[(size_t)(mbase + m + 3) * MD + n0 + nl];
    }
    pred[tid] = (a0 + a1) + (a2 + a3);
    __syncthreads();
    if (tid < 64)
        integ[(size_t)b * MD + n0 + tid] =
            pred[tid] + pred[tid + 64] + pred[tid + 128] + pred[tid + 192] + bias[n0 + tid];
}

// ---- Kernel E: LayerNorm ---------------------------------------------------
__global__ void k_ln(const float* __restrict__ integ, const float* __restrict__ gamma,
                     const float* __restrict__ beta, float* __restrict__ out) {
    __shared__ float red[8];
    const int tid = threadIdx.x, b = blockIdx.x;
    float v[4];
    #pragma unroll
    for (int k = 0; k < 4; ++k) v[k] = integ[(size_t)b * MD + tid + 256 * k];
    float s = v[0] + v[1] + v[2] + v[3];
    s = waveSum(s);
    const int wid = tid >> 6, lane = tid & 63;
    if (lane == 0) red[wid] = s;
    __syncthreads();
    const float mean = (red[0] + red[1] + red[2] + red[3]) * (1.f / MD);
    float q = 0.f;
    #pragma unroll
    for (int k = 0; k < 4; ++k) { float d = v[k] - mean; q += d * d; }
    q = waveSum(q);
    __syncthreads();
    if (lane == 0) red[4 + wid] = q;
    __syncthreads();
    const float var = (red[4] + red[5] + red[6] + red[7]) * (1.f / MD);
    const float rs = rsqrtf(var + LNEPS);
    #pragma unroll
    for (int k = 0; k < 4; ++k) {
        int i = tid + 256 * k;
        out[(size_t)b * MD + i] = (v[k] - mean) * rs * gamma[i] + beta[i];
    }
}

extern "C" void kernel_launch(void* const* d_in, const int* in_sizes, int n_in,
                              void* d_out, int out_size, void* d_ws, size_t ws_size,
                              hipStream_t stream) {
    const float* x     = (const float*)d_in[0];
    const float* wq    = (const float*)d_in[1];
    const float* wk    = (const float*)d_in[2];
    const float* wvp   = (const float*)d_in[3];
    const float* fcw   = (const float*)d_in[4];
    const float* fcb   = (const float*)d_in[5];
    const float* gamma = (const float*)d_in[6];
    const float* beta  = (const float*)d_in[7];
    const int*   idxp  = (const int*)d_in[8];
    float* out = (float*)d_out;

    const int sfull = in_sizes[0] / (B_ * MD);   // 4096

    float* q      = (float*)d_ws;
    float* wtil   = q      + (size_t)B_ * MD;
    float* scores = wtil   + (size_t)B_ * H_ * MD;
    float* concat = scores + (size_t)B_ * H_ * sfull;
    float* integ  = concat + (size_t)B_ * MD;
    float* fcwt   = integ  + (size_t)B_ * MD;

    hipLaunchKernelGGL(k_q,         dim3(4, 64),           dim3(256), 0, stream, x, wq, idxp, q, sfull);
    hipLaunchKernelGGL(k_wtil,      dim3(16, 32),          dim3(256), 0, stream, wk, q, wtil);
    hipLaunchKernelGGL(k_scores,    dim3(B_, (sfull + 1023) / 1024), dim3(256), 0, stream, x, wtil, idxp, scores, sfull);
    hipLaunchKernelGGL(k_transpose, dim3(32, 32),          dim3(256), 0, stream, fcw, fcwt);
    hipLaunchKernelGGL(k_attn,      dim3(H_, B_),          dim3(256), 0, stream, x, scores, wvp, idxp, concat, sfull);
    hipLaunchKernelGGL(k_fc,        dim3(64, 16),          dim3(256), 0, stream, concat, fcwt, fcb, integ);
    hipLaunchKernelGGL(k_ln,        dim3(B_),              dim3(256), 0, stream, integ, gamma, beta, out);
}

// Round 15
// 349.338 us; speedup vs baseline: 4.9718x; 1.0397x over previous
//
#include <hip/hip_runtime.h>
#include <math.h>

#define B_   64
#define MD   1024
#define H_   16
#define D_   64
#define LNEPS 1e-5f

// ---------------------------------------------------------------------------
// CHAMPION (R11 revert): 346 us. k_scores = v5 body (k=8, wave-private LDS,
// pad 20, zero barriers, depth-1 prefetch) + phase-ring stagger + XCD-b grid.
//
// ws layout (floats):
//   q      [64][1024]
//   wtil   [64][16][1024]
//   scores [64][16][sfull]
//   concat [64][1024]
//   integ  [64][1024]
//   fcwt   [1024][1024]
//
// LESSONS (R4..R14):
//  - LDS row pad must be a multiple of 4 floats (16 B) or b128 ops split.
//  - depth-2 reg prefetch, k=4, k=16, full-line 32-col chunks, zero-LDS:
//    all regressed. k_scores is pinned at ~290-320 us by the serialized
//    {vmcnt(0) drain -> LDS commit -> compute} wave batch structure; HIP
//    source cannot express counted-vmcnt pipelining around it.
//  - bf16/MFMA scores numerically unsafe (softmax winner flips).
// ---------------------------------------------------------------------------

__device__ __forceinline__ float waveMax(float v) {
    #pragma unroll
    for (int off = 32; off > 0; off >>= 1) v = fmaxf(v, __shfl_xor(v, off, 64));
    return v;
}
__device__ __forceinline__ float waveSum(float v) {
    #pragma unroll
    for (int off = 32; off > 0; off >>= 1) v += __shfl_xor(v, off, 64);
    return v;
}

// ---- Kernel A: q[b, col] = sum_m x[b, idx, m] * Wq[m, col] -----------------
// grid (4 col-chunks, 64 b), block 256
__global__ void k_q(const float* __restrict__ x, const float* __restrict__ wq,
                    const int* __restrict__ idxp, float* __restrict__ qout, int sfull) {
    const int tid = threadIdx.x;
    const int col = blockIdx.x * 256 + tid;
    const int b   = blockIdx.y;
    const int idx = *idxp;
    const float* xr = x + ((size_t)b * sfull + idx) * MD;   // uniform -> scalar loads
    float a0 = 0.f, a1 = 0.f, a2 = 0.f, a3 = 0.f;
    for (int m = 0; m < MD; m += 4) {
        a0 += xr[m]     * wq[(size_t)m * MD + col];
        a1 += xr[m + 1] * wq[(size_t)(m + 1) * MD + col];
        a2 += xr[m + 2] * wq[(size_t)(m + 2) * MD + col];
        a3 += xr[m + 3] * wq[(size_t)(m + 3) * MD + col];
    }
    qout[(size_t)b * MD + col] = (a0 + a1) + (a2 + a3);
}

// ---- Kernel B: wtil[b,h,m] = sum_d Wk[m, h*64+d] * q[b, h*64+d] ------------
// grid (16 h, 32 b-groups of 2), block 256
__global__ void k_wtil(const float* __restrict__ wk, const float* __restrict__ q,
                       float* __restrict__ wtil) {
    const int tid = threadIdx.x;
    const int h  = blockIdx.x;
    const int b0 = blockIdx.y * 2;
    for (int mi = 0; mi < 4; ++mi) {
        const int m = mi * 256 + tid;
        const float4* wrow = (const float4*)(wk + (size_t)m * MD + h * D_);
        float4 wv[16];
        #pragma unroll
        for (int j = 0; j < 16; ++j) wv[j] = wrow[j];
        #pragma unroll
        for (int bb = 0; bb < 2; ++bb) {
            const float* qh = q + (size_t)(b0 + bb) * MD + h * D_;  // uniform -> s_load
            float acc = 0.f;
            #pragma unroll
            for (int j = 0; j < 16; ++j)
                acc += wv[j].x * qh[4*j] + wv[j].y * qh[4*j+1]
                     + wv[j].z * qh[4*j+2] + wv[j].w * qh[4*j+3];
            wtil[((size_t)(b0 + bb) * H_ + h) * MD + m] = acc;
        }
    }
}

// ---- Kernel P1: scores[b,h,s] = (x[b,s,:] . wtil[b,h,:]) / 8 ---------------
// grid (64 b, sfull/512 s-tiles), block 256.
// Wave-private LDS, zero barriers, k=8 rows/thread, 16-col chunks, depth-1
// register prefetch, per-wave chunk-ring phase stagger (HBM channel
// decorrelation), grid transposed so linear id = b + 64*sy -> XCD = b%8
// (wtil slice stays L2-resident while x streams).
__global__ __launch_bounds__(256) void k_scores(
        const float* __restrict__ x, const float* __restrict__ wtil,
        const int* __restrict__ idxp, float* __restrict__ scores, int sfull) {
    __shared__ float Xw[4][128 * 20];  // per-wave: 128 rows x 16 m (+4 pad) = 10 KB
    __shared__ float Ww[4][16 * 20];   // per-wave: 16 h x 16 m (+4 pad) = 1.25 KB
    const int tid  = threadIdx.x;
    const int w    = tid >> 6;
    const int lane = tid & 63;
    const int sg   = lane & 15;      // s sub-index
    const int hg   = lane >> 4;      // h group
    const int b    = blockIdx.x;
    const int sblk = blockIdx.y * 512;
    const int s0   = sblk + w * 128; // this wave's first row
    const int S    = *idxp + 1;
    if (sblk >= S) return;

    const float* xb = x    + (size_t)b * sfull * MD;
    const float* wb = wtil + (size_t)b * H_ * MD;

    float* Xs = Xw[w];
    float* Ws = Ww[w];

    const int csl = lane >> 2;       // 0..15 staging row within group
    const int cf4 = lane & 3;        // 0..3 float4 slot

    // per-wave chunk-ring phase: decorrelate HBM channel usage
    const int phase = (b + blockIdx.y * 8 + w) & 63;
#define MCOF(T) ((((T) + phase) & 63) * 16)

    float acc[8][4] = {};
    float4 nx[8];
    float4 nw;

#define ISSUE(MC) do {                                                         \
        _Pragma("unroll")                                                      \
        for (int i = 0; i < 8; ++i) {                                          \
            int sl = i * 16 + csl;                                             \
            int srow = s0 + sl;                                                \
            nx[i] = (srow < S)                                                 \
                ? *(const float4*)(xb + (size_t)srow * MD + (MC) + cf4 * 4)    \
                : make_float4(0.f, 0.f, 0.f, 0.f);                             \
        }                                                                      \
        nw = *(const float4*)(wb + (size_t)csl * MD + (MC) + cf4 * 4);         \
    } while (0)

    ISSUE(MCOF(0));

    for (int t = 0; t < 64; ++t) {
        // commit staged regs to this wave's LDS slice (in-order after last
        // chunk's ds_reads; wave-private so no cross-wave hazard)
        #pragma unroll
        for (int i = 0; i < 8; ++i)
            *(float4*)(&Xs[(i * 16 + csl) * 20 + cf4 * 4]) = nx[i];
        *(float4*)(&Ws[csl * 20 + cf4 * 4]) = nw;

        if (t + 1 < 64) ISSUE(MCOF(t + 1));   // prefetch next ring chunk

        // compute 8s x 4h x 16m, in two 8-m halves to cap register pressure
        #pragma unroll
        for (int half = 0; half < 2; ++half) {
            float4 wrh[4][2];
            #pragma unroll
            for (int j = 0; j < 4; ++j) {
                #pragma unroll
                for (int mm = 0; mm < 2; ++mm)
                    wrh[j][mm] = *(const float4*)(&Ws[(hg + 4 * j) * 20 + (half * 2 + mm) * 4]);
            }
            #pragma unroll
            for (int k = 0; k < 8; ++k) {
                const float4 xr0 = *(const float4*)(&Xs[(sg + 16 * k) * 20 + (half * 2) * 4]);
                const float4 xr1 = *(const float4*)(&Xs[(sg + 16 * k) * 20 + (half * 2 + 1) * 4]);
                #pragma unroll
                for (int j = 0; j < 4; ++j) {
                    acc[k][j] += xr0.x * wrh[j][0].x + xr0.y * wrh[j][0].y
                               + xr0.z * wrh[j][0].z + xr0.w * wrh[j][0].w
                               + xr1.x * wrh[j][1].x + xr1.y * wrh[j][1].y
                               + xr1.z * wrh[j][1].z + xr1.w * wrh[j][1].w;
                }
            }
        }
    }
#undef ISSUE
#undef MCOF

    #pragma unroll
    for (int k = 0; k < 8; ++k) {
        const int s = s0 + sg + 16 * k;
        if (s < S) {
            #pragma unroll
            for (int j = 0; j < 4; ++j)
                scores[((size_t)b * H_ + (hg + 4 * j)) * sfull + s] = acc[k][j] * 0.125f;
        }
    }
}

// ---- Kernel C: softmax over s + sparse gather y = attn^T x + Wv projection -
// grid (16 h, 64 b), block 256
__global__ void k_attn(const float* __restrict__ x, const float* __restrict__ scores,
                       const float* __restrict__ wv, const int* __restrict__ idxp,
                       float* __restrict__ concat, int sfull) {
    __shared__ float red[8];
    __shared__ int   scanw[4];
    __shared__ int   lidx[4096];
    __shared__ float lw[4096];
    __shared__ float ylds[1024];
    __shared__ float pred[256];

    const int tid = threadIdx.x;
    const int h = blockIdx.x, b = blockIdx.y;
    const int S = *idxp + 1;
    const float* sc = scores + ((size_t)b * H_ + h) * sfull;

    float ls[16];
    float mx = -INFINITY;
    #pragma unroll
    for (int k = 0; k < 16; ++k) {
        int s = tid + 256 * k;
        if (s < S) { ls[k] = sc[s]; mx = fmaxf(mx, ls[k]); }
        else ls[k] = -INFINITY;
    }
    // block max
    mx = waveMax(mx);
    const int wid = tid >> 6, lane = tid & 63;
    if (lane == 0) red[wid] = mx;
    __syncthreads();
    mx = fmaxf(fmaxf(red[0], red[1]), fmaxf(red[2], red[3]));

    // denom + significant count (exp(s-max) <= 1.7e-15 contributes nothing)
    float sum = 0.f; int cnt = 0;
    #pragma unroll
    for (int k = 0; k < 16; ++k) {
        if (ls[k] > -INFINITY) {
            float e = ls[k] - mx;
            sum += expf(e);
            if (e > -34.f) ++cnt;
        }
    }
    sum = waveSum(sum);
    __syncthreads();
    if (lane == 0) red[4 + wid] = sum;
    __syncthreads();
    const float inv = 1.f / (red[4] + red[5] + red[6] + red[7]);

    // deterministic compaction: wave-level shfl scan + cross-wave LDS (1 barrier)
    int inc = cnt;
    #pragma unroll
    for (int off = 1; off < 64; off <<= 1) {
        int t = __shfl_up(inc, off, 64);
        if (lane >= off) inc += t;
    }
    if (lane == 63) scanw[wid] = inc;
    __syncthreads();
    int wbase = 0, total = 0;
    #pragma unroll
    for (int ww = 0; ww < 4; ++ww) {
        int t = scanw[ww];
        if (ww < wid) wbase += t;
        total += t;
    }
    int pos = wbase + inc - cnt;
    #pragma unroll
    for (int k = 0; k < 16; ++k) {
        if (ls[k] > -INFINITY) {
            float e = ls[k] - mx;
            if (e > -34.f) { lidx[pos] = tid + 256 * k; lw[pos] = expf(e) * inv; ++pos; }
        }
    }
    __syncthreads();

    // y[m] = sum_{significant s} attn * x[b,s,m]  (typically 1-3 rows)
    float4 acc = make_float4(0.f, 0.f, 0.f, 0.f);
    const float* xb = x + (size_t)b * sfull * MD;
    for (int e = 0; e < total; ++e) {
        int s = lidx[e]; float w = lw[e];
        float4 xv = *(const float4*)(xb + (size_t)s * MD + tid * 4);
        acc.x += w * xv.x; acc.y += w * xv.y; acc.z += w * xv.z; acc.w += w * xv.w;
    }
    *(float4*)(&ylds[tid * 4]) = acc;
    __syncthreads();

    // head_out[d] = sum_m y[m] * Wv[m, h*64+d]
    const int d = tid & 63, g = tid >> 6;
    const float* wcol = wv + (size_t)h * D_ + d;
    float part = 0.f;
    for (int m = g * 256; m < g * 256 + 256; ++m)
        part += ylds[m] * wcol[(size_t)m * MD];
    pred[tid] = part;
    __syncthreads();
    if (tid < 64) {
        float v = pred[tid] + pred[tid + 64] + pred[tid + 128] + pred[tid + 192];
        concat[(size_t)b * MD + h * D_ + tid] = v;
    }
}

// ---- Kernel T: fcwt[m][n] = fcW[n][m] --------------------------------------
__global__ void k_transpose(const float* __restrict__ a, float* __restrict__ at) {
    __shared__ float t[32][33];
    const int bx = blockIdx.x * 32, by = blockIdx.y * 32;
    const int tx = threadIdx.x & 31, ty = threadIdx.x >> 5;  // 32x8
    for (int r = ty; r < 32; r += 8)
        t[r][tx] = a[(size_t)(by + r) * MD + bx + tx];
    __syncthreads();
    for (int r = ty; r < 32; r += 8)
        at[(size_t)(bx + r) * MD + by + tx] = t[tx][r];
}

// ---- Kernel D: integ[b,n] = sum_m concat[b,m] * fcW[n,m] + bias[n] ---------
// grid (64 b, 16 n-chunks of 64), block 256: 4-way m-split + LDS reduce.
__global__ void k_fc(const float* __restrict__ concat, const float* __restrict__ fcwt,
                     const float* __restrict__ bias, float* __restrict__ integ) {
    __shared__ float c[1024];
    __shared__ float pred[256];
    const int tid = threadIdx.x, b = blockIdx.x;
    const int n0 = blockIdx.y * 64;
    const int nl = tid & 63, mg = tid >> 6;
    #pragma unroll
    for (int k = 0; k < 4; ++k) c[tid + 256 * k] = concat[(size_t)b * MD + tid + 256 * k];
    __syncthreads();
    const int mbase = mg * 256;
    float a0 = 0.f, a1 = 0.f, a2 = 0.f, a3 = 0.f;
    for (int m = 0; m < 256; m += 4) {
        a0 += c[mbase + m]     * fcwt[(size_t)(mbase + m) * MD + n0 + nl];
        a1 += c[mbase + m + 1] * fcwt[(size_t)(mbase + m + 1) * MD + n0 + nl];
        a2 += c[mbase + m + 2] * fcwt[(size_t)(mbase + m + 2) * MD + n0 + nl];
        a3 += c[mbase + m + 3] * fcwt[(size_t)(mbase + m + 3) * MD + n0 + nl];
    }
    pred[tid] = (a0 + a1) + (a2 + a3);
    __syncthreads();
    if (tid < 64)
        integ[(size_t)b * MD + n0 + tid] =
            pred[tid] + pred[tid + 64] + pred[tid + 128] + pred[tid + 192] + bias[n0 + tid];
}

// ---- Kernel E: LayerNorm ---------------------------------------------------
__global__ void k_ln(const float* __restrict__ integ, const float* __restrict__ gamma,
                     const float* __restrict__ beta, float* __restrict__ out) {
    __shared__ float red[8];
    const int tid = threadIdx.x, b = blockIdx.x;
    float v[4];
    #pragma unroll
    for (int k = 0; k < 4; ++k) v[k] = integ[(size_t)b * MD + tid + 256 * k];
    float s = v[0] + v[1] + v[2] + v[3];
    s = waveSum(s);
    const int wid = tid >> 6, lane = tid & 63;
    if (lane == 0) red[wid] = s;
    __syncthreads();
    const float mean = (red[0] + red[1] + red[2] + red[3]) * (1.f / MD);
    float q = 0.f;
    #pragma unroll
    for (int k = 0; k < 4; ++k) { float d = v[k] - mean; q += d * d; }
    q = waveSum(q);
    __syncthreads();
    if (lane == 0) red[4 + wid] = q;
    __syncthreads();
    const float var = (red[4] + red[5] + red[6] + red[7]) * (1.f / MD);
    const float rs = rsqrtf(var + LNEPS);
    #pragma unroll
    for (int k = 0; k < 4; ++k) {
        int i = tid + 256 * k;
        out[(size_t)b * MD + i] = (v[k] - mean) * rs * gamma[i] + beta[i];
    }
}

extern "C" void kernel_launch(void* const* d_in, const int* in_sizes, int n_in,
                              void* d_out, int out_size, void* d_ws, size_t ws_size,
                              hipStream_t stream) {
    const float* x     = (const float*)d_in[0];
    const float* wq    = (const float*)d_in[1];
    const float* wk    = (const float*)d_in[2];
    const float* wvp   = (const float*)d_in[3];
    const float* fcw   = (const float*)d_in[4];
    const float* fcb   = (const float*)d_in[5];
    const float* gamma = (const float*)d_in[6];
    const float* beta  = (const float*)d_in[7];
    const int*   idxp  = (const int*)d_in[8];
    float* out = (float*)d_out;

    const int sfull = in_sizes[0] / (B_ * MD);   // 4096

    float* q      = (float*)d_ws;
    float* wtil   = q      + (size_t)B_ * MD;
    float* scores = wtil   + (size_t)B_ * H_ * MD;
    float* concat = scores + (size_t)B_ * H_ * sfull;
    float* integ  = concat + (size_t)B_ * MD;
    float* fcwt   = integ  + (size_t)B_ * MD;

    hipLaunchKernelGGL(k_q,         dim3(4, 64),           dim3(256), 0, stream, x, wq, idxp, q, sfull);
    hipLaunchKernelGGL(k_wtil,      dim3(16, 32),          dim3(256), 0, stream, wk, q, wtil);
    hipLaunchKernelGGL(k_scores,    dim3(B_, (sfull + 511) / 512), dim3(256), 0, stream, x, wtil, idxp, scores, sfull);
    hipLaunchKernelGGL(k_transpose, dim3(32, 32),          dim3(256), 0, stream, fcw, fcwt);
    hipLaunchKernelGGL(k_attn,      dim3(H_, B_),          dim3(256), 0, stream, x, scores, wvp, idxp, concat, sfull);
    hipLaunchKernelGGL(k_fc,        dim3(64, 16),          dim3(256), 0, stream, concat, fcwt, fcb, integ);
    hipLaunchKernelGGL(k_ln,        dim3(B_),              dim3(256), 0, stream, integ, gamma, beta, out);
}